// Round 6
// baseline (376.720 us; speedup 1.0000x reference)
//
#include <hip/hip_runtime.h>
#include <math.h>

#define NPTS   65536
#define DIM    128
#define KCODES 4096

constexpr float DECAY_F         = 0.99f;
constexpr float ONE_MINUS_DECAY = 0.01f;
constexpr float EPS_F           = 1e-5f;

// d_out layout (floats): quantize_st[N*D] | embed_ind[N] | loss[1] | new_embed[K*D] | new_cluster_size[K]
constexpr int OFF_IDX  = NPTS * DIM;
constexpr int OFF_LOSS = OFF_IDX + NPTS;
constexpr int OFF_EMB  = OFF_LOSS + 1;
constexpr int OFF_NCS  = OFF_EMB + KCODES * DIM;

typedef _Float16 half8 __attribute__((ext_vector_type(8)));
typedef _Float16 half4 __attribute__((ext_vector_type(4)));
typedef float    f32x4 __attribute__((ext_vector_type(4)));

// ---------------- prep: E image + esq + ALL buffer init (no memsets) ----------------
__global__ __launch_bounds__(256) void vq_prep_kernel(const float* __restrict__ embed,
                                                      float* __restrict__ esq,
                                                      unsigned char* __restrict__ Eimg,
                                                      unsigned long long* __restrict__ rowpack,
                                                      unsigned int* __restrict__ counts,
                                                      float* __restrict__ out) {
    __shared__ float sq[512];
    int b = blockIdx.x, t = threadIdx.x;

    rowpack[b * 512 + t]       = ~0ULL;
    rowpack[b * 512 + 256 + t] = ~0ULL;
    if (t < 32) counts[b * 32 + t] = 0u;
    if (b == 0 && t == 0) out[OFF_LOSS] = 0.f;

    unsigned char* img = Eimg + ((size_t)b << 14);
#pragma unroll
    for (int it = 0; it < 2; ++it) {
        int idx = t + it * 256;            // 0..511 : (r 0..31, c8 0..15)
        int r = idx >> 4, c8 = idx & 15;
        const float4* src = (const float4*)(embed + (size_t)(b * 32 + r) * DIM + c8 * 8);
        float4 v0 = src[0], v1 = src[1];
        float e[8] = {v0.x, v0.y, v0.z, v0.w, v1.x, v1.y, v1.z, v1.w};
        half8 h8, l8;
        float ss = 0.f;
#pragma unroll
        for (int j = 0; j < 8; ++j) {
            _Float16 h = (_Float16)e[j];
            h8[j] = h;
            l8[j] = (_Float16)(e[j] - (float)h);
            ss = fmaf(e[j], e[j], ss);
        }
        int bo = r * 256 + ((c8 * 16) ^ ((r & 7) << 4));
        *(half8*)(img + bo)        = h8;
        *(half8*)(img + 8192 + bo) = l8;
        sq[idx] = ss;
    }
    __syncthreads();
    if (t < 32) {
        float s = 0.f;
#pragma unroll
        for (int c = 0; c < 16; ++c) s += sq[t * 16 + c];
        esq[b * 32 + t] = s;
    }
}

// ---------------- main: K-split MFMA argmin, 2-wave blocks, 64 rows/wave (rf=4) ----------------
// grid 1024: mblk = bid>>1 (128 rows), half = bid&1 (2048 codes). 4 blocks/CU.
__global__ __launch_bounds__(128, 2)
void vq_main_kernel(const float* __restrict__ x, const float* __restrict__ esq,
                    const unsigned char* __restrict__ Eimg,
                    unsigned long long* __restrict__ rowpack,
                    unsigned int* __restrict__ counts,
                    int* __restrict__ sidx,
                    float* __restrict__ out) {
    __shared__ __align__(16) unsigned char lds[32768];

    const int tid  = threadIdx.x;
    const int l    = tid & 63;
    const int w    = tid >> 6;          // 0..1
    const int mblk = blockIdx.x >> 1;
    const int half = blockIdx.x & 1;
    const int row0 = mblk * 128;

    // ---- X prologue: two 64-row phases through LDS; A = -2x f16 hi/lo -> 4 frags/wave ----
    half8 ahi[4][4], alo[4][4];
#pragma unroll
    for (int ph = 0; ph < 2; ++ph) {
        if (ph) __syncthreads();
        const float4* xg = (const float4*)(x + (size_t)(row0 + ph * 64) * DIM);
#pragma unroll
        for (int it = 0; it < 16; ++it) {
            int i4 = tid + it * 128;           // 0..2047 : 64 rows x 32 f4
            int r = i4 >> 5, c4 = i4 & 31;
            float4 v = xg[i4];
            float m0 = -2.f * v.x, m1 = -2.f * v.y, m2 = -2.f * v.z, m3 = -2.f * v.w;
            half4 h, lo;
            h[0] = (_Float16)m0; h[1] = (_Float16)m1; h[2] = (_Float16)m2; h[3] = (_Float16)m3;
            lo[0] = (_Float16)(m0 - (float)h[0]); lo[1] = (_Float16)(m1 - (float)h[1]);
            lo[2] = (_Float16)(m2 - (float)h[2]); lo[3] = (_Float16)(m3 - (float)h[3]);
            int bo = r * 256 + ((c4 * 8) ^ ((r & 7) << 4));
            *(half4*)(lds + bo)         = h;
            *(half4*)(lds + 16384 + bo) = lo;
        }
        __syncthreads();
        if (w == ph) {
#pragma unroll
            for (int rf = 0; rf < 4; ++rf)
#pragma unroll
                for (int ks = 0; ks < 4; ++ks) {
                    int rloc = rf * 16 + (l & 15);
                    int bo = rloc * 256 + ((ks * 64 + (l >> 4) * 16) ^ ((rloc & 7) << 4));
                    ahi[rf][ks] = *(const half8*)(lds + bo);
                    alo[rf][ks] = *(const half8*)(lds + 16384 + bo);
                }
        }
    }
    __syncthreads();   // lds becomes E double-buffer (16KB each)

#define STAGE(P, CT)                                                                     \
    {                                                                                    \
        const unsigned char* gsrc = Eimg + ((size_t)(half * 64 + (CT)) << 14);           \
        _Pragma("unroll")                                                                \
        for (int t = 0; t < 8; ++t) {                                                    \
            __builtin_amdgcn_global_load_lds(                                            \
                (const __attribute__((address_space(1))) unsigned int*)(gsrc + t * 2048 + w * 1024 + l * 16), \
                (__attribute__((address_space(3))) unsigned int*)(lds + (P) * 16384 + t * 2048 + w * 1024),   \
                16, 0, 0);                                                               \
        }                                                                                \
    }

    float minv[4][4];
    int   mini[4][4];
#pragma unroll
    for (int rf = 0; rf < 4; ++rf)
#pragma unroll
        for (int r = 0; r < 4; ++r) { minv[rf][r] = 3.4e38f; mini[rf][r] = 0; }

    STAGE(0, 0);
    __syncthreads();

    for (int ct = 0; ct < 64; ++ct) {
        int p = ct & 1;
        if (ct < 63) STAGE(p ^ 1, ct + 1);
        const unsigned char* bb = lds + p * 16384;

        float ecf[2];
#pragma unroll
        for (int cf = 0; cf < 2; ++cf) ecf[cf] = esq[half * 2048 + ct * 32 + cf * 16 + (l & 15)];

        f32x4 acc[4][2];
#pragma unroll
        for (int rf = 0; rf < 4; ++rf)
#pragma unroll
            for (int cf = 0; cf < 2; ++cf) acc[rf][cf] = (f32x4){0.f, 0.f, 0.f, 0.f};

#pragma unroll
        for (int ks = 0; ks < 4; ++ks) {
#pragma unroll
            for (int cf = 0; cf < 2; ++cf) {
                int rowb = cf * 16 + (l & 15);
                int bo = rowb * 256 + ((ks * 64 + (l >> 4) * 16) ^ ((rowb & 7) << 4));
                half8 bh = *(const half8*)(bb + bo);
                half8 bl = *(const half8*)(bb + 8192 + bo);
#pragma unroll
                for (int rf = 0; rf < 4; ++rf)
                    acc[rf][cf] = __builtin_amdgcn_mfma_f32_16x16x32_f16(ahi[rf][ks], bh, acc[rf][cf], 0, 0, 0);
#pragma unroll
                for (int rf = 0; rf < 4; ++rf)
                    acc[rf][cf] = __builtin_amdgcn_mfma_f32_16x16x32_f16(alo[rf][ks], bh, acc[rf][cf], 0, 0, 0);
#pragma unroll
                for (int rf = 0; rf < 4; ++rf)
                    acc[rf][cf] = __builtin_amdgcn_mfma_f32_16x16x32_f16(ahi[rf][ks], bl, acc[rf][cf], 0, 0, 0);
            }
        }

#pragma unroll
        for (int rf = 0; rf < 4; ++rf)
#pragma unroll
            for (int cf = 0; cf < 2; ++cf) {
                int kidx = half * 2048 + ct * 32 + cf * 16 + (l & 15);
#pragma unroll
                for (int r = 0; r < 4; ++r) {
                    float v = ecf[cf] + acc[rf][cf][r];
                    if (v < minv[rf][r]) { minv[rf][r] = v; mini[rf][r] = kidx; }
                }
            }

        __syncthreads();   // drains staging vmcnt + protects buffer reuse
    }

    // argmin reduce across the 16 col-lanes (low 4 lane bits)
#pragma unroll
    for (int off = 1; off < 16; off <<= 1) {
#pragma unroll
        for (int rf = 0; rf < 4; ++rf)
#pragma unroll
            for (int r = 0; r < 4; ++r) {
                float v2 = __shfl_xor(minv[rf][r], off);
                int   i2 = __shfl_xor(mini[rf][r], off);
                if (v2 < minv[rf][r] || (v2 == minv[rf][r] && i2 < mini[rf][r])) {
                    minv[rf][r] = v2; mini[rf][r] = i2;
                }
            }
    }
    // combine halves: key = (monotonic(score)<<32)|idx, atomicMin; second arriver finishes.
    if ((l & 15) == 0) {
#pragma unroll
        for (int rf = 0; rf < 4; ++rf)
#pragma unroll
            for (int r = 0; r < 4; ++r) {
                int row = row0 + w * 64 + rf * 16 + (l >> 4) * 4 + r;   // C/D: row=(l>>4)*4+reg
                unsigned int u = __float_as_uint(minv[rf][r]);
                u = (u & 0x80000000u) ? ~u : (u | 0x80000000u);
                unsigned long long key = ((unsigned long long)u << 32) | (unsigned int)mini[rf][r];
                unsigned long long old = atomicMin(&rowpack[row], key);
                if (old != ~0ULL) {
                    unsigned long long fin = old < key ? old : key;
                    int kf = (int)(fin & 0xFFFFFFFFu);
                    out[OFF_IDX + row] = (float)kf;
                    sidx[row] = kf;
                    atomicAdd(&counts[kf], 1u);
                }
            }
    }
}

// ---------------- scan: prefix-sum counts -> offsets/cursor; ncs, inv_sm ----------------
__global__ __launch_bounds__(1024) void vq_scan_kernel(const unsigned int* __restrict__ counts,
                                                       const float* __restrict__ cs,
                                                       float* __restrict__ out,
                                                       int* __restrict__ offsets,
                                                       int* __restrict__ cursor,
                                                       float* __restrict__ inv_sm) {
    __shared__ int   redi[1024];
    __shared__ float redf[1024];
    int tid = threadIdx.x;

    unsigned int c[4];
    float vl[4];
    int   csum = 0;
    float nsum = 0.f;
#pragma unroll
    for (int j = 0; j < 4; ++j) {
        int i = tid * 4 + j;
        c[j] = counts[i];
        csum += (int)c[j];
        float v = fmaf(cs[i], DECAY_F, (float)c[j] * ONE_MINUS_DECAY);
        vl[j] = v;
        nsum += v;
        out[OFF_NCS + i] = v;
    }

    redi[tid] = csum;
    redf[tid] = nsum;
    __syncthreads();
    for (int s = 1; s < 1024; s <<= 1) {
        int v = (tid >= s) ? redi[tid - s] : 0;
        __syncthreads();
        redi[tid] += v;
        __syncthreads();
    }
    int excl = redi[tid] - csum;

    for (int s = 512; s >= 1; s >>= 1) {
        if (tid < s) redf[tid] += redf[tid + s];
        __syncthreads();
    }
    float ntot = redf[0];
    float num  = ntot + (float)KCODES * EPS_F;

    int off = excl;
#pragma unroll
    for (int j = 0; j < 4; ++j) {
        int i = tid * 4 + j;
        offsets[i] = off;
        cursor[i]  = off;
        off += (int)c[j];
        inv_sm[i] = num / ((vl[j] + EPS_F) * ntot);
    }
}

// ---------------- sortq: bucket rows + coalesced quantize gather + commit loss ----------------
// 1024 blocks x 256 thr; block owns 64 rows (4 thr/row for the copy phase).
__global__ __launch_bounds__(256) void vq_sortq_kernel(const float* __restrict__ x,
                                                       const float* __restrict__ embed,
                                                       const int* __restrict__ sidx,
                                                       int* __restrict__ cursor,
                                                       int* __restrict__ rowids,
                                                       float* __restrict__ out) {
    __shared__ float red[256];
    __shared__ int   ks_s[64];
    int tid = threadIdx.x;

    if (tid < 64) {
        int rr = blockIdx.x * 64 + tid;
        int k = sidx[rr];
        ks_s[tid] = k;
        int pos = atomicAdd(&cursor[k], 1);
        rowids[pos] = rr;
    }
    __syncthreads();

    int r  = blockIdx.x * 64 + (tid >> 2);
    int k  = ks_s[tid >> 2];
    int dq = (tid & 3) * 8;

    const float4* eg = (const float4*)embed + (size_t)k * 32 + dq;
    const float4* xg = (const float4*)x + (size_t)r * 32 + dq;
    float4*       qg = (float4*)out + (size_t)r * 32 + dq;

    float lsum = 0.f;
#pragma unroll
    for (int j = 0; j < 8; ++j) {
        float4 q = eg[j], xv = xg[j];
        qg[j] = q;
        float d0 = q.x - xv.x, d1 = q.y - xv.y, d2 = q.z - xv.z, d3 = q.w - xv.w;
        lsum += d0 * d0 + d1 * d1 + d2 * d2 + d3 * d3;
    }
    red[tid] = lsum;
    __syncthreads();
    for (int s = 128; s >= 1; s >>= 1) {
        if (tid < s) red[tid] += red[tid + s];
        __syncthreads();
    }
    if (tid == 0) atomicAdd(out + OFF_LOSS, red[0] * (1.0f / ((float)NPTS * (float)DIM)));
}

// ---------------- segsum: one wave per code; embed_sum + EMA + smoothing ----------------
__global__ __launch_bounds__(256) void vq_segsum_kernel(const float* __restrict__ x,
                                                        const float* __restrict__ eavg,
                                                        const int* __restrict__ rowids,
                                                        const int* __restrict__ offsets,
                                                        const unsigned int* __restrict__ counts,
                                                        const float* __restrict__ inv_sm,
                                                        float* __restrict__ out) {
    int w = threadIdx.x >> 6, l = threadIdx.x & 63;
    int k = blockIdx.x * 4 + w;
    int off = offsets[k];
    int cnt = (int)counts[k];

    float a0 = 0.f, a1 = 0.f, b0 = 0.f, b1 = 0.f;
    int i = 0;
    for (; i + 2 <= cnt; i += 2) {
        int r0 = rowids[off + i], r1 = rowids[off + i + 1];
        float2 v0 = *(const float2*)(x + (size_t)r0 * DIM + l * 2);
        float2 v1 = *(const float2*)(x + (size_t)r1 * DIM + l * 2);
        a0 += v0.x; a1 += v0.y;
        b0 += v1.x; b1 += v1.y;
    }
    if (i < cnt) {
        int r0 = rowids[off + i];
        float2 v0 = *(const float2*)(x + (size_t)r0 * DIM + l * 2);
        a0 += v0.x; a1 += v0.y;
    }
    a0 += b0; a1 += b1;

    float2 ev = *(const float2*)(eavg + (size_t)k * DIM + l * 2);
    float ism = inv_sm[k];
    float2 o;
    o.x = fmaf(ev.x, DECAY_F, a0 * ONE_MINUS_DECAY) * ism;
    o.y = fmaf(ev.y, DECAY_F, a1 * ONE_MINUS_DECAY) * ism;
    *(float2*)(out + OFF_EMB + (size_t)k * DIM + l * 2) = o;
}

extern "C" void kernel_launch(void* const* d_in, const int* in_sizes, int n_in,
                              void* d_out, int out_size, void* d_ws, size_t ws_size,
                              hipStream_t stream) {
    const float* x     = (const float*)d_in[0];
    const float* embed = (const float*)d_in[1];
    const float* cs    = (const float*)d_in[2];
    const float* eavg  = (const float*)d_in[3];
    float* out = (float*)d_out;

    // ws: rowpack[N] u64 | esq[K] | inv_sm[K] | counts[K] | offsets[K] | cursor[K] |
    //     rowids[N] | sidx[N] | Eimg 2MB   (~3.1 MB)
    unsigned long long* rowpack = (unsigned long long*)d_ws;
    float*         esq     = (float*)(rowpack + NPTS);
    float*         inv_sm  = esq + KCODES;
    unsigned int*  counts  = (unsigned int*)(inv_sm + KCODES);
    int*           offsets = (int*)(counts + KCODES);
    int*           cursor  = offsets + KCODES;
    int*           rowids  = cursor + KCODES;
    int*           sidx    = rowids + NPTS;
    unsigned char* Eimg    = (unsigned char*)(sidx + NPTS);

    vq_prep_kernel<<<KCODES / 32, 256, 0, stream>>>(embed, esq, Eimg, rowpack, counts, out);
    vq_main_kernel<<<NPTS / 128 * 2, 128, 0, stream>>>(x, esq, Eimg, rowpack, counts, sidx, out);
    vq_scan_kernel<<<1, 1024, 0, stream>>>(counts, cs, out, offsets, cursor, inv_sm);
    vq_sortq_kernel<<<NPTS / 64, 256, 0, stream>>>(x, embed, sidx, cursor, rowids, out);
    vq_segsum_kernel<<<KCODES / 4, 256, 0, stream>>>(x, eavg, rowids, offsets, counts, inv_sm, out);
}

// Round 7
// 341.560 us; speedup vs baseline: 1.1029x; 1.1029x over previous
//
#include <hip/hip_runtime.h>
#include <math.h>

#define NPTS   65536
#define DIM    128
#define KCODES 4096

constexpr float DECAY_F         = 0.99f;
constexpr float ONE_MINUS_DECAY = 0.01f;
constexpr float EPS_F           = 1e-5f;

// d_out layout (floats): quantize_st[N*D] | embed_ind[N] | loss[1] | new_embed[K*D] | new_cluster_size[K]
constexpr int OFF_IDX  = NPTS * DIM;
constexpr int OFF_LOSS = OFF_IDX + NPTS;
constexpr int OFF_EMB  = OFF_LOSS + 1;
constexpr int OFF_NCS  = OFF_EMB + KCODES * DIM;

typedef _Float16 half8 __attribute__((ext_vector_type(8)));
typedef _Float16 half4 __attribute__((ext_vector_type(4)));
typedef float    f32x4 __attribute__((ext_vector_type(4)));

// ---------------- prep: E image + esq + ALL buffer init (no memsets) ----------------
__global__ __launch_bounds__(256) void vq_prep_kernel(const float* __restrict__ embed,
                                                      float* __restrict__ esq,
                                                      unsigned char* __restrict__ Eimg,
                                                      unsigned long long* __restrict__ rowpack,
                                                      unsigned int* __restrict__ counts,
                                                      float* __restrict__ out) {
    __shared__ float sq[512];
    int b = blockIdx.x, t = threadIdx.x;

    rowpack[b * 512 + t]       = ~0ULL;
    rowpack[b * 512 + 256 + t] = ~0ULL;
    if (t < 32) counts[b * 32 + t] = 0u;
    if (b == 0 && t == 0) out[OFF_LOSS] = 0.f;

    unsigned char* img = Eimg + ((size_t)b << 14);
#pragma unroll
    for (int it = 0; it < 2; ++it) {
        int idx = t + it * 256;            // 0..511 : (r 0..31, c8 0..15)
        int r = idx >> 4, c8 = idx & 15;
        const float4* src = (const float4*)(embed + (size_t)(b * 32 + r) * DIM + c8 * 8);
        float4 v0 = src[0], v1 = src[1];
        float e[8] = {v0.x, v0.y, v0.z, v0.w, v1.x, v1.y, v1.z, v1.w};
        half8 h8, l8;
        float ss = 0.f;
#pragma unroll
        for (int j = 0; j < 8; ++j) {
            _Float16 h = (_Float16)e[j];
            h8[j] = h;
            l8[j] = (_Float16)(e[j] - (float)h);
            ss = fmaf(e[j], e[j], ss);
        }
        int bo = r * 256 + ((c8 * 16) ^ ((r & 7) << 4));
        *(half8*)(img + bo)        = h8;
        *(half8*)(img + 8192 + bo) = l8;
        sq[idx] = ss;
    }
    __syncthreads();
    if (t < 32) {
        float s = 0.f;
#pragma unroll
        for (int c = 0; c < 16; ++c) s += sq[t * 16 + c];
        esq[b * 32 + t] = s;
    }
}

// ---------------- main: K-split MFMA argmin (R5 shape: 4 waves, 32 rows/wave) ----------------
// grid 1024: mblk = bid>>1 (128 rows), half = bid&1 (2048 codes).
__global__ __launch_bounds__(256, 4)
void vq_main_kernel(const float* __restrict__ x, const float* __restrict__ esq,
                    const unsigned char* __restrict__ Eimg,
                    unsigned long long* __restrict__ rowpack,
                    unsigned int* __restrict__ counts,
                    int* __restrict__ sidx,
                    float* __restrict__ out) {
    __shared__ __align__(16) unsigned char lds[32768];

    const int tid  = threadIdx.x;
    const int l    = tid & 63;
    const int w    = tid >> 6;          // 0..3
    const int mblk = blockIdx.x >> 1;
    const int half = blockIdx.x & 1;
    const int row0 = mblk * 128;

    // ---- X prologue: two 64-row phases through LDS; A = -2x f16 hi/lo -> registers ----
    half8 ahi[2][4], alo[2][4];
#pragma unroll
    for (int ph = 0; ph < 2; ++ph) {
        if (ph) __syncthreads();
        const float4* xg = (const float4*)(x + (size_t)(row0 + ph * 64) * DIM);
#pragma unroll
        for (int it = 0; it < 8; ++it) {
            int i4 = tid + it * 256;           // 0..2047 : 64 rows x 32 f4
            int r = i4 >> 5, c4 = i4 & 31;
            float4 v = xg[i4];
            float m0 = -2.f * v.x, m1 = -2.f * v.y, m2 = -2.f * v.z, m3 = -2.f * v.w;
            half4 h, lo;
            h[0] = (_Float16)m0; h[1] = (_Float16)m1; h[2] = (_Float16)m2; h[3] = (_Float16)m3;
            lo[0] = (_Float16)(m0 - (float)h[0]); lo[1] = (_Float16)(m1 - (float)h[1]);
            lo[2] = (_Float16)(m2 - (float)h[2]); lo[3] = (_Float16)(m3 - (float)h[3]);
            int bo = r * 256 + ((c4 * 8) ^ ((r & 7) << 4));
            *(half4*)(lds + bo)         = h;
            *(half4*)(lds + 16384 + bo) = lo;
        }
        __syncthreads();
        if ((w >> 1) == ph) {
#pragma unroll
            for (int rf = 0; rf < 2; ++rf)
#pragma unroll
                for (int ks = 0; ks < 4; ++ks) {
                    int rloc = (w & 1) * 32 + rf * 16 + (l & 15);
                    int bo = rloc * 256 + ((ks * 64 + (l >> 4) * 16) ^ ((rloc & 7) << 4));
                    ahi[rf][ks] = *(const half8*)(lds + bo);
                    alo[rf][ks] = *(const half8*)(lds + 16384 + bo);
                }
        }
    }
    __syncthreads();   // lds becomes E double-buffer (16KB each)

#define STAGE(P, CT)                                                                     \
    {                                                                                    \
        const unsigned char* gsrc = Eimg + ((size_t)(half * 64 + (CT)) << 14);           \
        _Pragma("unroll")                                                                \
        for (int t = 0; t < 4; ++t) {                                                    \
            __builtin_amdgcn_global_load_lds(                                            \
                (const __attribute__((address_space(1))) unsigned int*)(gsrc + t * 4096 + w * 1024 + l * 16), \
                (__attribute__((address_space(3))) unsigned int*)(lds + (P) * 16384 + t * 4096 + w * 1024),   \
                16, 0, 0);                                                               \
        }                                                                                \
    }

    float minv[2][4];
    int   mini[2][4];
#pragma unroll
    for (int rf = 0; rf < 2; ++rf)
#pragma unroll
        for (int r = 0; r < 4; ++r) { minv[rf][r] = 3.4e38f; mini[rf][r] = 0; }

    STAGE(0, 0);
    __syncthreads();

    for (int ct = 0; ct < 64; ++ct) {
        int p = ct & 1;
        if (ct < 63) STAGE(p ^ 1, ct + 1);
        const unsigned char* bb = lds + p * 16384;

        float ecf[2];
#pragma unroll
        for (int cf = 0; cf < 2; ++cf) ecf[cf] = esq[half * 2048 + ct * 32 + cf * 16 + (l & 15)];

        // esq folded into accumulator init: score = esq + sum(A*E) accumulates directly
        f32x4 acc[2][2];
#pragma unroll
        for (int rf = 0; rf < 2; ++rf)
#pragma unroll
            for (int cf = 0; cf < 2; ++cf) {
                float e = ecf[cf];
                acc[rf][cf] = (f32x4){e, e, e, e};
            }

        __builtin_amdgcn_s_setprio(1);
#pragma unroll
        for (int ks = 0; ks < 4; ++ks) {
#pragma unroll
            for (int cf = 0; cf < 2; ++cf) {
                int rowb = cf * 16 + (l & 15);
                int bo = rowb * 256 + ((ks * 64 + (l >> 4) * 16) ^ ((rowb & 7) << 4));
                half8 bh = *(const half8*)(bb + bo);
                half8 bl = *(const half8*)(bb + 8192 + bo);
                acc[0][cf] = __builtin_amdgcn_mfma_f32_16x16x32_f16(ahi[0][ks], bh, acc[0][cf], 0, 0, 0);
                acc[1][cf] = __builtin_amdgcn_mfma_f32_16x16x32_f16(ahi[1][ks], bh, acc[1][cf], 0, 0, 0);
                acc[0][cf] = __builtin_amdgcn_mfma_f32_16x16x32_f16(alo[0][ks], bh, acc[0][cf], 0, 0, 0);
                acc[1][cf] = __builtin_amdgcn_mfma_f32_16x16x32_f16(alo[1][ks], bh, acc[1][cf], 0, 0, 0);
                acc[0][cf] = __builtin_amdgcn_mfma_f32_16x16x32_f16(ahi[0][ks], bl, acc[0][cf], 0, 0, 0);
                acc[1][cf] = __builtin_amdgcn_mfma_f32_16x16x32_f16(ahi[1][ks], bl, acc[1][cf], 0, 0, 0);
            }
        }
        __builtin_amdgcn_s_setprio(0);

#pragma unroll
        for (int rf = 0; rf < 2; ++rf)
#pragma unroll
            for (int cf = 0; cf < 2; ++cf) {
                int kidx = half * 2048 + ct * 32 + cf * 16 + (l & 15);
#pragma unroll
                for (int r = 0; r < 4; ++r) {
                    float v = acc[rf][cf][r];
                    if (v < minv[rf][r]) { minv[rf][r] = v; mini[rf][r] = kidx; }
                }
            }

        __syncthreads();   // drains staging vmcnt + protects buffer reuse
    }

    // argmin reduce across the 16 col-lanes (low 4 lane bits)
#pragma unroll
    for (int off = 1; off < 16; off <<= 1) {
#pragma unroll
        for (int rf = 0; rf < 2; ++rf)
#pragma unroll
            for (int r = 0; r < 4; ++r) {
                float v2 = __shfl_xor(minv[rf][r], off);
                int   i2 = __shfl_xor(mini[rf][r], off);
                if (v2 < minv[rf][r] || (v2 == minv[rf][r] && i2 < mini[rf][r])) {
                    minv[rf][r] = v2; mini[rf][r] = i2;
                }
            }
    }
    // combine halves: key = (monotonic(score)<<32)|idx, atomicMin; second arriver finishes.
    if ((l & 15) == 0) {
#pragma unroll
        for (int rf = 0; rf < 2; ++rf)
#pragma unroll
            for (int r = 0; r < 4; ++r) {
                int row = row0 + w * 32 + rf * 16 + (l >> 4) * 4 + r;   // C/D: row=(l>>4)*4+reg
                unsigned int u = __float_as_uint(minv[rf][r]);
                u = (u & 0x80000000u) ? ~u : (u | 0x80000000u);
                unsigned long long key = ((unsigned long long)u << 32) | (unsigned int)mini[rf][r];
                unsigned long long old = atomicMin(&rowpack[row], key);
                if (old != ~0ULL) {
                    unsigned long long fin = old < key ? old : key;
                    int kf = (int)(fin & 0xFFFFFFFFu);
                    out[OFF_IDX + row] = (float)kf;
                    sidx[row] = kf;
                    atomicAdd(&counts[kf], 1u);
                }
            }
    }
}

// ---------------- scan: shfl-based prefix sum of counts; ncs, inv_sm ----------------
// single block, 256 threads (4 waves), 16 codes/thread.
__global__ __launch_bounds__(256) void vq_scan_kernel(const unsigned int* __restrict__ counts,
                                                      const float* __restrict__ cs,
                                                      float* __restrict__ out,
                                                      int* __restrict__ offsets,
                                                      int* __restrict__ cursor,
                                                      float* __restrict__ inv_sm) {
    __shared__ int   wsum[4];
    __shared__ float wnsum[4];
    int tid = threadIdx.x, l = tid & 63, w = tid >> 6;

    unsigned int c[16];
    float vl[16];
    int   csum = 0;
    float nsum = 0.f;
#pragma unroll
    for (int j = 0; j < 16; ++j) {
        int i = tid * 16 + j;
        c[j] = counts[i];
        csum += (int)c[j];
        float v = fmaf(cs[i], DECAY_F, (float)c[j] * ONE_MINUS_DECAY);
        vl[j] = v;
        nsum += v;
        out[OFF_NCS + i] = v;
    }

    // wave-inclusive scan of per-thread sums
    int inc = csum;
#pragma unroll
    for (int off = 1; off < 64; off <<= 1) {
        int t = __shfl_up(inc, off);
        if (l >= off) inc += t;
    }
    // wave reduce of nsum
    float nred = nsum;
#pragma unroll
    for (int off = 32; off >= 1; off >>= 1) nred += __shfl_xor(nred, off);

    if (l == 63) wsum[w] = inc;
    if (l == 0)  wnsum[w] = nred;
    __syncthreads();

    int wpre = 0;
    for (int i = 0; i < w; ++i) wpre += wsum[i];
    float ntot = wnsum[0] + wnsum[1] + wnsum[2] + wnsum[3];
    float num  = ntot + (float)KCODES * EPS_F;

    int off_ = wpre + inc - csum;   // exclusive prefix for this thread's first code
#pragma unroll
    for (int j = 0; j < 16; ++j) {
        int i = tid * 16 + j;
        offsets[i] = off_;
        cursor[i]  = off_;
        off_ += (int)c[j];
        inv_sm[i] = num / ((vl[j] + EPS_F) * ntot);
    }
}

// ---------------- sort: bucket rows by code via cursor (tiny) ----------------
__global__ __launch_bounds__(256) void vq_sort_kernel(const int* __restrict__ sidx,
                                                      int* __restrict__ cursor,
                                                      int* __restrict__ rowids) {
    int r = blockIdx.x * 256 + threadIdx.x;
    int k = sidx[r];
    int pos = atomicAdd(&cursor[k], 1);
    rowids[pos] = r;
}

// ---------------- segsumq: one block (4 waves) per code ----------------
// rows striped across waves (4x straggler reduction); fused quantize + loss +
// embed_sum + EMA + smoothing; new_embed written once, no element atomics.
__global__ __launch_bounds__(256) void vq_segsumq_kernel(const float* __restrict__ x,
                                                         const float* __restrict__ embed,
                                                         const float* __restrict__ eavg,
                                                         const int* __restrict__ rowids,
                                                         const int* __restrict__ offsets,
                                                         const unsigned int* __restrict__ counts,
                                                         const float* __restrict__ inv_sm,
                                                         float* __restrict__ out) {
    __shared__ float2 accs[4][64];
    __shared__ float  lred[4];
    int tid = threadIdx.x, w = tid >> 6, l = tid & 63;
    int k   = blockIdx.x;
    int off = offsets[k];
    int cnt = (int)counts[k];

    float2 e2 = *(const float2*)(embed + (size_t)k * DIM + l * 2);

    float a0 = 0.f, a1 = 0.f, lsum = 0.f;
    for (int i = w; i < cnt; i += 4) {
        int r = rowids[off + i];
        float2 v = *(const float2*)(x + (size_t)r * DIM + l * 2);
        *(float2*)(out + (size_t)r * DIM + l * 2) = e2;   // quantize gather
        a0 += v.x; a1 += v.y;
        float d0 = e2.x - v.x, d1 = e2.y - v.y;
        lsum = fmaf(d0, d0, fmaf(d1, d1, lsum));
    }
    accs[w][l] = (float2){a0, a1};

#pragma unroll
    for (int s = 32; s >= 1; s >>= 1) lsum += __shfl_xor(lsum, s);
    if (l == 0) lred[w] = lsum;
    __syncthreads();

    if (tid < 64) {
        float2 s0 = accs[0][l], s1 = accs[1][l], s2 = accs[2][l], s3 = accs[3][l];
        float sx = (s0.x + s1.x) + (s2.x + s3.x);
        float sy = (s0.y + s1.y) + (s2.y + s3.y);
        float2 ev = *(const float2*)(eavg + (size_t)k * DIM + l * 2);
        float ism = inv_sm[k];
        float2 o;
        o.x = fmaf(ev.x, DECAY_F, sx * ONE_MINUS_DECAY) * ism;
        o.y = fmaf(ev.y, DECAY_F, sy * ONE_MINUS_DECAY) * ism;
        *(float2*)(out + OFF_EMB + (size_t)k * DIM + l * 2) = o;
    }
    if (tid == 0) {
        float bl = (lred[0] + lred[1]) + (lred[2] + lred[3]);
        if (bl != 0.f) atomicAdd(out + OFF_LOSS, bl * (1.0f / ((float)NPTS * (float)DIM)));
    }
}

extern "C" void kernel_launch(void* const* d_in, const int* in_sizes, int n_in,
                              void* d_out, int out_size, void* d_ws, size_t ws_size,
                              hipStream_t stream) {
    const float* x     = (const float*)d_in[0];
    const float* embed = (const float*)d_in[1];
    const float* cs    = (const float*)d_in[2];
    const float* eavg  = (const float*)d_in[3];
    float* out = (float*)d_out;

    // ws: rowpack[N] u64 | esq[K] | inv_sm[K] | counts[K] | offsets[K] | cursor[K] |
    //     rowids[N] | sidx[N] | Eimg 2MB   (~3.1 MB)
    unsigned long long* rowpack = (unsigned long long*)d_ws;
    float*         esq     = (float*)(rowpack + NPTS);
    float*         inv_sm  = esq + KCODES;
    unsigned int*  counts  = (unsigned int*)(inv_sm + KCODES);
    int*           offsets = (int*)(counts + KCODES);
    int*           cursor  = offsets + KCODES;
    int*           rowids  = cursor + KCODES;
    int*           sidx    = rowids + NPTS;
    unsigned char* Eimg    = (unsigned char*)(sidx + NPTS);

    vq_prep_kernel<<<KCODES / 32, 256, 0, stream>>>(embed, esq, Eimg, rowpack, counts, out);
    vq_main_kernel<<<NPTS / 128 * 2, 256, 0, stream>>>(x, esq, Eimg, rowpack, counts, sidx, out);
    vq_scan_kernel<<<1, 256, 0, stream>>>(counts, cs, out, offsets, cursor, inv_sm);
    vq_sort_kernel<<<NPTS / 256, 256, 0, stream>>>(sidx, cursor, rowids);
    vq_segsumq_kernel<<<KCODES, 256, 0, stream>>>(x, embed, eavg, rowids, offsets, counts, inv_sm, out);
}

// Round 8
// 250.945 us; speedup vs baseline: 1.5012x; 1.3611x over previous
//
#include <hip/hip_runtime.h>
#include <math.h>

#define NPTS   65536
#define DIM    128
#define KCODES 4096

constexpr float DECAY_F         = 0.99f;
constexpr float ONE_MINUS_DECAY = 0.01f;
constexpr float EPS_F           = 1e-5f;

// d_out layout (floats): quantize_st[N*D] | embed_ind[N] | loss[1] | new_embed[K*D] | new_cluster_size[K]
constexpr int OFF_IDX  = NPTS * DIM;
constexpr int OFF_LOSS = OFF_IDX + NPTS;
constexpr int OFF_EMB  = OFF_LOSS + 1;
constexpr int OFF_NCS  = OFF_EMB + KCODES * DIM;

typedef _Float16 half8 __attribute__((ext_vector_type(8)));
typedef _Float16 half4 __attribute__((ext_vector_type(4)));
typedef float    f32x4 __attribute__((ext_vector_type(4)));

// ---------------- prep: E image + esq + ALL buffer init (no memsets) ----------------
__global__ __launch_bounds__(256) void vq_prep_kernel(const float* __restrict__ embed,
                                                      float* __restrict__ esq,
                                                      unsigned char* __restrict__ Eimg,
                                                      unsigned long long* __restrict__ rowpack,
                                                      unsigned int* __restrict__ counts,
                                                      float* __restrict__ esum,
                                                      float* __restrict__ out) {
    __shared__ float sq[512];
    int b = blockIdx.x, t = threadIdx.x;

    rowpack[b * 512 + t]       = ~0ULL;
    rowpack[b * 512 + 256 + t] = ~0ULL;
    if (t < 32) counts[b * 32 + t] = 0u;
    if (b == 0 && t == 0) out[OFF_LOSS] = 0.f;

    // zero esum (K*D floats = 131072 float4s over 128 blocks x 256 thr)
    {
        float4* ez = (float4*)esum;
#pragma unroll
        for (int j = 0; j < 4; ++j) ez[(size_t)b * 1024 + j * 256 + t] = (float4){0.f, 0.f, 0.f, 0.f};
    }

    unsigned char* img = Eimg + ((size_t)b << 14);
#pragma unroll
    for (int it = 0; it < 2; ++it) {
        int idx = t + it * 256;            // 0..511 : (r 0..31, c8 0..15)
        int r = idx >> 4, c8 = idx & 15;
        const float4* src = (const float4*)(embed + (size_t)(b * 32 + r) * DIM + c8 * 8);
        float4 v0 = src[0], v1 = src[1];
        float e[8] = {v0.x, v0.y, v0.z, v0.w, v1.x, v1.y, v1.z, v1.w};
        half8 h8, l8;
        float ss = 0.f;
#pragma unroll
        for (int j = 0; j < 8; ++j) {
            _Float16 h = (_Float16)e[j];
            h8[j] = h;
            l8[j] = (_Float16)(e[j] - (float)h);
            ss = fmaf(e[j], e[j], ss);
        }
        int bo = r * 256 + ((c8 * 16) ^ ((r & 7) << 4));
        *(half8*)(img + bo)        = h8;
        *(half8*)(img + 8192 + bo) = l8;
        sq[idx] = ss;
    }
    __syncthreads();
    if (t < 32) {
        float s = 0.f;
#pragma unroll
        for (int c = 0; c < 16; ++c) s += sq[t * 16 + c];
        esq[b * 32 + t] = s;
    }
}

// ---------------- main: K-split MFMA argmin (unchanged from R7, 183us proven) ----------------
__global__ __launch_bounds__(256, 4)
void vq_main_kernel(const float* __restrict__ x, const float* __restrict__ esq,
                    const unsigned char* __restrict__ Eimg,
                    unsigned long long* __restrict__ rowpack,
                    unsigned int* __restrict__ counts,
                    int* __restrict__ sidx,
                    float* __restrict__ out) {
    __shared__ __align__(16) unsigned char lds[32768];

    const int tid  = threadIdx.x;
    const int l    = tid & 63;
    const int w    = tid >> 6;          // 0..3
    const int mblk = blockIdx.x >> 1;
    const int half = blockIdx.x & 1;
    const int row0 = mblk * 128;

    half8 ahi[2][4], alo[2][4];
#pragma unroll
    for (int ph = 0; ph < 2; ++ph) {
        if (ph) __syncthreads();
        const float4* xg = (const float4*)(x + (size_t)(row0 + ph * 64) * DIM);
#pragma unroll
        for (int it = 0; it < 8; ++it) {
            int i4 = tid + it * 256;           // 0..2047 : 64 rows x 32 f4
            int r = i4 >> 5, c4 = i4 & 31;
            float4 v = xg[i4];
            float m0 = -2.f * v.x, m1 = -2.f * v.y, m2 = -2.f * v.z, m3 = -2.f * v.w;
            half4 h, lo;
            h[0] = (_Float16)m0; h[1] = (_Float16)m1; h[2] = (_Float16)m2; h[3] = (_Float16)m3;
            lo[0] = (_Float16)(m0 - (float)h[0]); lo[1] = (_Float16)(m1 - (float)h[1]);
            lo[2] = (_Float16)(m2 - (float)h[2]); lo[3] = (_Float16)(m3 - (float)h[3]);
            int bo = r * 256 + ((c4 * 8) ^ ((r & 7) << 4));
            *(half4*)(lds + bo)         = h;
            *(half4*)(lds + 16384 + bo) = lo;
        }
        __syncthreads();
        if ((w >> 1) == ph) {
#pragma unroll
            for (int rf = 0; rf < 2; ++rf)
#pragma unroll
                for (int ks = 0; ks < 4; ++ks) {
                    int rloc = (w & 1) * 32 + rf * 16 + (l & 15);
                    int bo = rloc * 256 + ((ks * 64 + (l >> 4) * 16) ^ ((rloc & 7) << 4));
                    ahi[rf][ks] = *(const half8*)(lds + bo);
                    alo[rf][ks] = *(const half8*)(lds + 16384 + bo);
                }
        }
    }
    __syncthreads();   // lds becomes E double-buffer (16KB each)

#define STAGE(P, CT)                                                                     \
    {                                                                                    \
        const unsigned char* gsrc = Eimg + ((size_t)(half * 64 + (CT)) << 14);           \
        _Pragma("unroll")                                                                \
        for (int t = 0; t < 4; ++t) {                                                    \
            __builtin_amdgcn_global_load_lds(                                            \
                (const __attribute__((address_space(1))) unsigned int*)(gsrc + t * 4096 + w * 1024 + l * 16), \
                (__attribute__((address_space(3))) unsigned int*)(lds + (P) * 16384 + t * 4096 + w * 1024),   \
                16, 0, 0);                                                               \
        }                                                                                \
    }

    float minv[2][4];
    int   mini[2][4];
#pragma unroll
    for (int rf = 0; rf < 2; ++rf)
#pragma unroll
        for (int r = 0; r < 4; ++r) { minv[rf][r] = 3.4e38f; mini[rf][r] = 0; }

    STAGE(0, 0);
    __syncthreads();

    for (int ct = 0; ct < 64; ++ct) {
        int p = ct & 1;
        if (ct < 63) STAGE(p ^ 1, ct + 1);
        const unsigned char* bb = lds + p * 16384;

        float ecf[2];
#pragma unroll
        for (int cf = 0; cf < 2; ++cf) ecf[cf] = esq[half * 2048 + ct * 32 + cf * 16 + (l & 15)];

        f32x4 acc[2][2];
#pragma unroll
        for (int rf = 0; rf < 2; ++rf)
#pragma unroll
            for (int cf = 0; cf < 2; ++cf) {
                float e = ecf[cf];
                acc[rf][cf] = (f32x4){e, e, e, e};
            }

        __builtin_amdgcn_s_setprio(1);
#pragma unroll
        for (int ks = 0; ks < 4; ++ks) {
#pragma unroll
            for (int cf = 0; cf < 2; ++cf) {
                int rowb = cf * 16 + (l & 15);
                int bo = rowb * 256 + ((ks * 64 + (l >> 4) * 16) ^ ((rowb & 7) << 4));
                half8 bh = *(const half8*)(bb + bo);
                half8 bl = *(const half8*)(bb + 8192 + bo);
                acc[0][cf] = __builtin_amdgcn_mfma_f32_16x16x32_f16(ahi[0][ks], bh, acc[0][cf], 0, 0, 0);
                acc[1][cf] = __builtin_amdgcn_mfma_f32_16x16x32_f16(ahi[1][ks], bh, acc[1][cf], 0, 0, 0);
                acc[0][cf] = __builtin_amdgcn_mfma_f32_16x16x32_f16(alo[0][ks], bh, acc[0][cf], 0, 0, 0);
                acc[1][cf] = __builtin_amdgcn_mfma_f32_16x16x32_f16(alo[1][ks], bh, acc[1][cf], 0, 0, 0);
                acc[0][cf] = __builtin_amdgcn_mfma_f32_16x16x32_f16(ahi[0][ks], bl, acc[0][cf], 0, 0, 0);
                acc[1][cf] = __builtin_amdgcn_mfma_f32_16x16x32_f16(ahi[1][ks], bl, acc[1][cf], 0, 0, 0);
            }
        }
        __builtin_amdgcn_s_setprio(0);

#pragma unroll
        for (int rf = 0; rf < 2; ++rf)
#pragma unroll
            for (int cf = 0; cf < 2; ++cf) {
                int kidx = half * 2048 + ct * 32 + cf * 16 + (l & 15);
#pragma unroll
                for (int r = 0; r < 4; ++r) {
                    float v = acc[rf][cf][r];
                    if (v < minv[rf][r]) { minv[rf][r] = v; mini[rf][r] = kidx; }
                }
            }

        __syncthreads();
    }

#pragma unroll
    for (int off = 1; off < 16; off <<= 1) {
#pragma unroll
        for (int rf = 0; rf < 2; ++rf)
#pragma unroll
            for (int r = 0; r < 4; ++r) {
                float v2 = __shfl_xor(minv[rf][r], off);
                int   i2 = __shfl_xor(mini[rf][r], off);
                if (v2 < minv[rf][r] || (v2 == minv[rf][r] && i2 < mini[rf][r])) {
                    minv[rf][r] = v2; mini[rf][r] = i2;
                }
            }
    }
    if ((l & 15) == 0) {
#pragma unroll
        for (int rf = 0; rf < 2; ++rf)
#pragma unroll
            for (int r = 0; r < 4; ++r) {
                int row = row0 + w * 32 + rf * 16 + (l >> 4) * 4 + r;   // C/D: row=(l>>4)*4+reg
                unsigned int u = __float_as_uint(minv[rf][r]);
                u = (u & 0x80000000u) ? ~u : (u | 0x80000000u);
                unsigned long long key = ((unsigned long long)u << 32) | (unsigned int)mini[rf][r];
                unsigned long long old = atomicMin(&rowpack[row], key);
                if (old != ~0ULL) {
                    unsigned long long fin = old < key ? old : key;
                    int kf = (int)(fin & 0xFFFFFFFFu);
                    out[OFF_IDX + row] = (float)kf;
                    sidx[row] = kf;
                    atomicAdd(&counts[kf], 1u);
                }
            }
    }
}

// ---------------- scan: shfl-based prefix sum of counts; ncs, inv_sm ----------------
__global__ __launch_bounds__(256) void vq_scan_kernel(const unsigned int* __restrict__ counts,
                                                      const float* __restrict__ cs,
                                                      float* __restrict__ out,
                                                      int* __restrict__ offsets,
                                                      int* __restrict__ cursor,
                                                      float* __restrict__ inv_sm) {
    __shared__ int   wsum[4];
    __shared__ float wnsum[4];
    int tid = threadIdx.x, l = tid & 63, w = tid >> 6;

    unsigned int c[16];
    float vl[16];
    int   csum = 0;
    float nsum = 0.f;
#pragma unroll
    for (int j = 0; j < 16; ++j) {
        int i = tid * 16 + j;
        c[j] = counts[i];
        csum += (int)c[j];
        float v = fmaf(cs[i], DECAY_F, (float)c[j] * ONE_MINUS_DECAY);
        vl[j] = v;
        nsum += v;
        out[OFF_NCS + i] = v;
    }

    int inc = csum;
#pragma unroll
    for (int off = 1; off < 64; off <<= 1) {
        int t = __shfl_up(inc, off);
        if (l >= off) inc += t;
    }
    float nred = nsum;
#pragma unroll
    for (int off = 32; off >= 1; off >>= 1) nred += __shfl_xor(nred, off);

    if (l == 63) wsum[w] = inc;
    if (l == 0)  wnsum[w] = nred;
    __syncthreads();

    int wpre = 0;
    for (int i = 0; i < w; ++i) wpre += wsum[i];
    float ntot = wnsum[0] + wnsum[1] + wnsum[2] + wnsum[3];
    float num  = ntot + (float)KCODES * EPS_F;

    int off_ = wpre + inc - csum;
#pragma unroll
    for (int j = 0; j < 16; ++j) {
        int i = tid * 16 + j;
        offsets[i] = off_;
        cursor[i]  = off_;
        off_ += (int)c[j];
        inv_sm[i] = num / ((vl[j] + EPS_F) * ntot);
    }
}

// ---------------- sort: bucket rows by code; emit rowids + skey ----------------
__global__ __launch_bounds__(256) void vq_sort_kernel(const int* __restrict__ sidx,
                                                      int* __restrict__ cursor,
                                                      int* __restrict__ rowids,
                                                      int* __restrict__ skey) {
    int r = blockIdx.x * 256 + threadIdx.x;
    int k = sidx[r];
    int pos = atomicAdd(&cursor[k], 1);
    rowids[pos] = r;
    skey[pos]   = k;
}

// ---------------- segsum: position-parallel sorted segment sum ----------------
// block = 64 sorted positions (uniform work). LDS buckets by local segment rank;
// interior buckets -> plain store to esum; <=2 edge buckets -> global atomics.
// Fused: quantize gather + commit loss.
__global__ __launch_bounds__(256) void vq_segsum_kernel(const float* __restrict__ x,
                                                        const float* __restrict__ embed,
                                                        const int* __restrict__ rowids,
                                                        const int* __restrict__ skey,
                                                        const int* __restrict__ offsets,
                                                        const unsigned int* __restrict__ counts,
                                                        float* __restrict__ esum,
                                                        float* __restrict__ out) {
    __shared__ float buck[64][DIM];     // 32 KB
    __shared__ int   rid_s[64], rank_s[64], bcode_s[64];
    __shared__ int   nseg_s;
    __shared__ float lred[4];

    const int tid = threadIdx.x;
    const int w   = tid >> 6, l = tid & 63;
    const int p0  = blockIdx.x * 64;

    // zero buckets
    {
        float4* bz = (float4*)&buck[0][0];
#pragma unroll
        for (int j = 0; j < 8; ++j) bz[j * 256 + tid] = (float4){0.f, 0.f, 0.f, 0.f};
    }

    // segment ranks via wave-0 prefix scan of code-change flags
    if (tid < 64) {
        int p = p0 + tid;
        int k = skey[p];
        rid_s[tid] = rowids[p];
        int f = (tid == 0) ? 1 : (k != skey[p - 1] ? 1 : 0);
        int inc = f;
#pragma unroll
        for (int off = 1; off < 64; off <<= 1) {
            int t = __shfl_up(inc, off);
            if (tid >= off) inc += t;
        }
        int rank = inc - 1;
        rank_s[tid] = rank;
        if (f) bcode_s[rank] = k;
        if (tid == 63) nseg_s = inc;
    }
    __syncthreads();

    // accumulate rows: wave w owns positions 16w..16w+15; lane l owns dims (2l, 2l+1)
    float lsum = 0.f;
#pragma unroll 4
    for (int i = 0; i < 16; ++i) {
        int pl = w * 16 + i;
        int r  = rid_s[pl];
        int b  = rank_s[pl];
        int k  = bcode_s[b];
        float2 xv = *(const float2*)(x + (size_t)r * DIM + l * 2);
        float2 ev = *(const float2*)(embed + (size_t)k * DIM + l * 2);
        *(float2*)(out + (size_t)r * DIM + l * 2) = ev;     // quantize gather
        atomicAdd(&buck[b][l * 2],     xv.x);               // LDS ds_add_f32
        atomicAdd(&buck[b][l * 2 + 1], xv.y);
        float d0 = ev.x - xv.x, d1 = ev.y - xv.y;
        lsum = fmaf(d0, d0, fmaf(d1, d1, lsum));
    }

#pragma unroll
    for (int s = 32; s >= 1; s >>= 1) lsum += __shfl_xor(lsum, s);
    if (l == 0) lred[w] = lsum;
    __syncthreads();

    // flush buckets: wave-strided; contained -> plain store, edge -> atomicAdd
    int nseg = nseg_s;
    for (int b = w; b < nseg; b += 4) {
        int kb = bcode_s[b];
        int o  = offsets[kb];
        int c  = (int)counts[kb];
        float v0 = buck[b][l * 2], v1 = buck[b][l * 2 + 1];
        if (o >= p0 && o + c <= p0 + 64) {
            *(float2*)(esum + (size_t)kb * DIM + l * 2) = (float2){v0, v1};
        } else {
            atomicAdd(esum + (size_t)kb * DIM + l * 2,     v0);
            atomicAdd(esum + (size_t)kb * DIM + l * 2 + 1, v1);
        }
    }

    if (tid == 0) {
        float bl = (lred[0] + lred[1]) + (lred[2] + lred[3]);
        atomicAdd(out + OFF_LOSS, bl * (1.0f / ((float)NPTS * (float)DIM)));
    }
}

// ---------------- embed: new_embed = (eavg*0.99 + esum*0.01) * inv_sm ----------------
__global__ __launch_bounds__(256) void vq_embed_kernel(const float* __restrict__ eavg,
                                                       const float* __restrict__ esum,
                                                       const float* __restrict__ inv_sm,
                                                       float* __restrict__ out) {
    int i = blockIdx.x * 256 + threadIdx.x;
    int k = i >> 7;
    out[OFF_EMB + i] = fmaf(eavg[i], DECAY_F, esum[i] * ONE_MINUS_DECAY) * inv_sm[k];
}

extern "C" void kernel_launch(void* const* d_in, const int* in_sizes, int n_in,
                              void* d_out, int out_size, void* d_ws, size_t ws_size,
                              hipStream_t stream) {
    const float* x     = (const float*)d_in[0];
    const float* embed = (const float*)d_in[1];
    const float* cs    = (const float*)d_in[2];
    const float* eavg  = (const float*)d_in[3];
    float* out = (float*)d_out;

    // ws: rowpack[N] u64 | esq[K] | inv_sm[K] | counts[K] | offsets[K] | cursor[K] |
    //     rowids[N] | sidx[N] | skey[N] | esum[K*D] | Eimg 2MB   (~5.9 MB)
    unsigned long long* rowpack = (unsigned long long*)d_ws;
    float*         esq     = (float*)(rowpack + NPTS);
    float*         inv_sm  = esq + KCODES;
    unsigned int*  counts  = (unsigned int*)(inv_sm + KCODES);
    int*           offsets = (int*)(counts + KCODES);
    int*           cursor  = offsets + KCODES;
    int*           rowids  = cursor + KCODES;
    int*           sidx    = rowids + NPTS;
    int*           skey    = sidx + NPTS;
    float*         esum    = (float*)(skey + NPTS);
    unsigned char* Eimg    = (unsigned char*)(esum + KCODES * DIM);

    vq_prep_kernel<<<KCODES / 32, 256, 0, stream>>>(embed, esq, Eimg, rowpack, counts, esum, out);
    vq_main_kernel<<<NPTS / 128 * 2, 256, 0, stream>>>(x, esq, Eimg, rowpack, counts, sidx, out);
    vq_scan_kernel<<<1, 256, 0, stream>>>(counts, cs, out, offsets, cursor, inv_sm);
    vq_sort_kernel<<<NPTS / 256, 256, 0, stream>>>(sidx, cursor, rowids, skey);
    vq_segsum_kernel<<<NPTS / 64, 256, 0, stream>>>(x, embed, rowids, skey, offsets, counts, esum, out);
    vq_embed_kernel<<<(KCODES * DIM) / 256, 256, 0, stream>>>(eavg, esum, inv_sm, out);
}

// Round 9
// 222.157 us; speedup vs baseline: 1.6957x; 1.1296x over previous
//
#include <hip/hip_runtime.h>
#include <math.h>

#define NPTS   65536
#define DIM    128
#define KCODES 4096

constexpr float DECAY_F         = 0.99f;
constexpr float ONE_MINUS_DECAY = 0.01f;
constexpr float EPS_F           = 1e-5f;

// d_out layout (floats): quantize_st[N*D] | embed_ind[N] | loss[1] | new_embed[K*D] | new_cluster_size[K]
constexpr int OFF_IDX  = NPTS * DIM;
constexpr int OFF_LOSS = OFF_IDX + NPTS;
constexpr int OFF_EMB  = OFF_LOSS + 1;
constexpr int OFF_NCS  = OFF_EMB + KCODES * DIM;

typedef _Float16 half8 __attribute__((ext_vector_type(8)));
typedef _Float16 half4 __attribute__((ext_vector_type(4)));
typedef float    f32x4 __attribute__((ext_vector_type(4)));

// ---------------- prep: E image + esq + ALL buffer init (no memsets) ----------------
__global__ __launch_bounds__(256) void vq_prep_kernel(const float* __restrict__ embed,
                                                      float* __restrict__ esq,
                                                      unsigned char* __restrict__ Eimg,
                                                      unsigned long long* __restrict__ rowpack,
                                                      unsigned int* __restrict__ counts,
                                                      float* __restrict__ esum,
                                                      float* __restrict__ out) {
    __shared__ float sq[512];
    int b = blockIdx.x, t = threadIdx.x;

    rowpack[b * 512 + t]       = ~0ULL;
    rowpack[b * 512 + 256 + t] = ~0ULL;
    if (t < 32) counts[b * 32 + t] = 0u;
    if (b == 0 && t == 0) out[OFF_LOSS] = 0.f;

    {
        float4* ez = (float4*)esum;
#pragma unroll
        for (int j = 0; j < 4; ++j) ez[(size_t)b * 1024 + j * 256 + t] = (float4){0.f, 0.f, 0.f, 0.f};
    }

    unsigned char* img = Eimg + ((size_t)b << 14);
#pragma unroll
    for (int it = 0; it < 2; ++it) {
        int idx = t + it * 256;            // 0..511 : (r 0..31, c8 0..15)
        int r = idx >> 4, c8 = idx & 15;
        const float4* src = (const float4*)(embed + (size_t)(b * 32 + r) * DIM + c8 * 8);
        float4 v0 = src[0], v1 = src[1];
        float e[8] = {v0.x, v0.y, v0.z, v0.w, v1.x, v1.y, v1.z, v1.w};
        half8 h8, l8;
        float ss = 0.f;
#pragma unroll
        for (int j = 0; j < 8; ++j) {
            _Float16 h = (_Float16)e[j];
            h8[j] = h;
            l8[j] = (_Float16)(e[j] - (float)h);
            ss = fmaf(e[j], e[j], ss);
        }
        int bo = r * 256 + ((c8 * 16) ^ ((r & 7) << 4));
        *(half8*)(img + bo)        = h8;
        *(half8*)(img + 8192 + bo) = l8;
        sq[idx] = ss;
    }
    __syncthreads();
    if (t < 32) {
        float s = 0.f;
#pragma unroll
        for (int c = 0; c < 16; ++c) s += sq[t * 16 + c];
        esq[b * 32 + t] = s;
    }
}

// ---------------- main: K-split MFMA argmin; esq in LDS; counted-vmcnt 2-barrier loop ----------------
__global__ __launch_bounds__(256, 4)
void vq_main_kernel(const float* __restrict__ x, const float* __restrict__ esq,
                    const unsigned char* __restrict__ Eimg,
                    unsigned long long* __restrict__ rowpack,
                    unsigned int* __restrict__ counts,
                    int* __restrict__ sidx,
                    float* __restrict__ out) {
    __shared__ __align__(16) unsigned char lds[40960];   // 32KB E dbuf + 8KB esq

    const int tid  = threadIdx.x;
    const int l    = tid & 63;
    const int w    = tid >> 6;          // 0..3
    const int mblk = blockIdx.x >> 1;
    const int half = blockIdx.x & 1;
    const int row0 = mblk * 128;

    // esq for this half -> LDS (no vmcnt ops in main loop besides staging)
    {
        const float4* eq = (const float4*)(esq + half * 2048);
        float4* dst = (float4*)(lds + 32768);
        dst[tid]       = eq[tid];
        dst[tid + 256] = eq[tid + 256];
    }

    // ---- X prologue: two 64-row phases through LDS; A = -2x f16 hi/lo -> registers ----
    half8 ahi[2][4], alo[2][4];
#pragma unroll
    for (int ph = 0; ph < 2; ++ph) {
        if (ph) __syncthreads();
        const float4* xg = (const float4*)(x + (size_t)(row0 + ph * 64) * DIM);
#pragma unroll
        for (int it = 0; it < 8; ++it) {
            int i4 = tid + it * 256;           // 0..2047 : 64 rows x 32 f4
            int r = i4 >> 5, c4 = i4 & 31;
            float4 v = xg[i4];
            float m0 = -2.f * v.x, m1 = -2.f * v.y, m2 = -2.f * v.z, m3 = -2.f * v.w;
            half4 h, lo;
            h[0] = (_Float16)m0; h[1] = (_Float16)m1; h[2] = (_Float16)m2; h[3] = (_Float16)m3;
            lo[0] = (_Float16)(m0 - (float)h[0]); lo[1] = (_Float16)(m1 - (float)h[1]);
            lo[2] = (_Float16)(m2 - (float)h[2]); lo[3] = (_Float16)(m3 - (float)h[3]);
            int bo = r * 256 + ((c4 * 8) ^ ((r & 7) << 4));
            *(half4*)(lds + bo)         = h;
            *(half4*)(lds + 16384 + bo) = lo;
        }
        __syncthreads();
        if ((w >> 1) == ph) {
#pragma unroll
            for (int rf = 0; rf < 2; ++rf)
#pragma unroll
                for (int ks = 0; ks < 4; ++ks) {
                    int rloc = (w & 1) * 32 + rf * 16 + (l & 15);
                    int bo = rloc * 256 + ((ks * 64 + (l >> 4) * 16) ^ ((rloc & 7) << 4));
                    ahi[rf][ks] = *(const half8*)(lds + bo);
                    alo[rf][ks] = *(const half8*)(lds + 16384 + bo);
                }
        }
    }
    __syncthreads();   // lds[0..32768] becomes E double-buffer (16KB each)

#define STAGE(P, CT)                                                                     \
    {                                                                                    \
        const unsigned char* gsrc = Eimg + ((size_t)(half * 64 + (CT)) << 14);           \
        _Pragma("unroll")                                                                \
        for (int t = 0; t < 4; ++t) {                                                    \
            __builtin_amdgcn_global_load_lds(                                            \
                (const __attribute__((address_space(1))) unsigned int*)(gsrc + t * 4096 + w * 1024 + l * 16), \
                (__attribute__((address_space(3))) unsigned int*)(lds + (P) * 16384 + t * 4096 + w * 1024),   \
                16, 0, 0);                                                               \
        }                                                                                \
    }

    float minv[2][4];
    int   mini[2][4];
#pragma unroll
    for (int rf = 0; rf < 2; ++rf)
#pragma unroll
        for (int r = 0; r < 4; ++r) { minv[rf][r] = 3.4e38f; mini[rf][r] = 0; }

    const float* esql = (const float*)(lds + 32768);
    STAGE(0, 0);

    for (int ct = 0; ct < 64; ++ct) {
        const int p = ct & 1;
        // issue next tile, then wait only for the PREVIOUS stage (counted vmcnt, T4)
        if (ct < 63) {
            STAGE(p ^ 1, ct + 1);
            asm volatile("s_waitcnt vmcnt(4)" ::: "memory");
        } else {
            asm volatile("s_waitcnt vmcnt(0)" ::: "memory");
        }
        __builtin_amdgcn_s_barrier();   // all waves' tile-p loads landed

        const unsigned char* bb = lds + p * 16384;

        float ecf[2];
        ecf[0] = esql[ct * 32 + (l & 15)];
        ecf[1] = esql[ct * 32 + 16 + (l & 15)];

        f32x4 acc[2][2];
#pragma unroll
        for (int rf = 0; rf < 2; ++rf)
#pragma unroll
            for (int cf = 0; cf < 2; ++cf) {
                float e = ecf[cf];
                acc[rf][cf] = (f32x4){e, e, e, e};
            }

        __builtin_amdgcn_s_setprio(1);
#pragma unroll
        for (int ks = 0; ks < 4; ++ks) {
#pragma unroll
            for (int cf = 0; cf < 2; ++cf) {
                int rowb = cf * 16 + (l & 15);
                int bo = rowb * 256 + ((ks * 64 + (l >> 4) * 16) ^ ((rowb & 7) << 4));
                half8 bh = *(const half8*)(bb + bo);
                half8 bl = *(const half8*)(bb + 8192 + bo);
                acc[0][cf] = __builtin_amdgcn_mfma_f32_16x16x32_f16(ahi[0][ks], bh, acc[0][cf], 0, 0, 0);
                acc[1][cf] = __builtin_amdgcn_mfma_f32_16x16x32_f16(ahi[1][ks], bh, acc[1][cf], 0, 0, 0);
                acc[0][cf] = __builtin_amdgcn_mfma_f32_16x16x32_f16(alo[0][ks], bh, acc[0][cf], 0, 0, 0);
                acc[1][cf] = __builtin_amdgcn_mfma_f32_16x16x32_f16(alo[1][ks], bh, acc[1][cf], 0, 0, 0);
                acc[0][cf] = __builtin_amdgcn_mfma_f32_16x16x32_f16(ahi[0][ks], bl, acc[0][cf], 0, 0, 0);
                acc[1][cf] = __builtin_amdgcn_mfma_f32_16x16x32_f16(ahi[1][ks], bl, acc[1][cf], 0, 0, 0);
            }
        }
        __builtin_amdgcn_s_setprio(0);

#pragma unroll
        for (int rf = 0; rf < 2; ++rf)
#pragma unroll
            for (int cf = 0; cf < 2; ++cf) {
                int kidx = half * 2048 + ct * 32 + cf * 16 + (l & 15);
#pragma unroll
                for (int r = 0; r < 4; ++r) {
                    float v = acc[rf][cf][r];
                    if (v < minv[rf][r]) { minv[rf][r] = v; mini[rf][r] = kidx; }
                }
            }

        __builtin_amdgcn_s_barrier();   // all reads of tile p done -> safe to overwrite
    }

#pragma unroll
    for (int off = 1; off < 16; off <<= 1) {
#pragma unroll
        for (int rf = 0; rf < 2; ++rf)
#pragma unroll
            for (int r = 0; r < 4; ++r) {
                float v2 = __shfl_xor(minv[rf][r], off);
                int   i2 = __shfl_xor(mini[rf][r], off);
                if (v2 < minv[rf][r] || (v2 == minv[rf][r] && i2 < mini[rf][r])) {
                    minv[rf][r] = v2; mini[rf][r] = i2;
                }
            }
    }
    if ((l & 15) == 0) {
#pragma unroll
        for (int rf = 0; rf < 2; ++rf)
#pragma unroll
            for (int r = 0; r < 4; ++r) {
                int row = row0 + w * 32 + rf * 16 + (l >> 4) * 4 + r;   // C/D: row=(l>>4)*4+reg
                unsigned int u = __float_as_uint(minv[rf][r]);
                u = (u & 0x80000000u) ? ~u : (u | 0x80000000u);
                unsigned long long key = ((unsigned long long)u << 32) | (unsigned int)mini[rf][r];
                unsigned long long old = atomicMin(&rowpack[row], key);
                if (old != ~0ULL) {
                    unsigned long long fin = old < key ? old : key;
                    int kf = (int)(fin & 0xFFFFFFFFu);
                    out[OFF_IDX + row] = (float)kf;
                    sidx[row] = kf;
                    atomicAdd(&counts[kf], 1u);
                }
            }
    }
}

// ---------------- scan: shfl-based prefix sum of counts; ncs, inv_sm ----------------
__global__ __launch_bounds__(256) void vq_scan_kernel(const unsigned int* __restrict__ counts,
                                                      const float* __restrict__ cs,
                                                      float* __restrict__ out,
                                                      int* __restrict__ offsets,
                                                      int* __restrict__ cursor,
                                                      float* __restrict__ inv_sm) {
    __shared__ int   wsum[4];
    __shared__ float wnsum[4];
    int tid = threadIdx.x, l = tid & 63, w = tid >> 6;

    unsigned int c[16];
    float vl[16];
    int   csum = 0;
    float nsum = 0.f;
#pragma unroll
    for (int j = 0; j < 16; ++j) {
        int i = tid * 16 + j;
        c[j] = counts[i];
        csum += (int)c[j];
        float v = fmaf(cs[i], DECAY_F, (float)c[j] * ONE_MINUS_DECAY);
        vl[j] = v;
        nsum += v;
        out[OFF_NCS + i] = v;
    }

    int inc = csum;
#pragma unroll
    for (int off = 1; off < 64; off <<= 1) {
        int t = __shfl_up(inc, off);
        if (l >= off) inc += t;
    }
    float nred = nsum;
#pragma unroll
    for (int off = 32; off >= 1; off >>= 1) nred += __shfl_xor(nred, off);

    if (l == 63) wsum[w] = inc;
    if (l == 0)  wnsum[w] = nred;
    __syncthreads();

    int wpre = 0;
    for (int i = 0; i < w; ++i) wpre += wsum[i];
    float ntot = wnsum[0] + wnsum[1] + wnsum[2] + wnsum[3];
    float num  = ntot + (float)KCODES * EPS_F;

    int off_ = wpre + inc - csum;
#pragma unroll
    for (int j = 0; j < 16; ++j) {
        int i = tid * 16 + j;
        offsets[i] = off_;
        cursor[i]  = off_;
        off_ += (int)c[j];
        inv_sm[i] = num / ((vl[j] + EPS_F) * ntot);
    }
}

// ---------------- sort: bucket rows by code; emit rowids + skey ----------------
__global__ __launch_bounds__(256) void vq_sort_kernel(const int* __restrict__ sidx,
                                                      int* __restrict__ cursor,
                                                      int* __restrict__ rowids,
                                                      int* __restrict__ skey) {
    int r = blockIdx.x * 256 + threadIdx.x;
    int k = sidx[r];
    int pos = atomicAdd(&cursor[k], 1);
    rowids[pos] = r;
    skey[pos]   = k;
}

// ---------------- segsum: position-parallel sorted segment sum (run-flush) ----------------
__global__ __launch_bounds__(256) void vq_segsum_kernel(const float* __restrict__ x,
                                                        const float* __restrict__ embed,
                                                        const int* __restrict__ rowids,
                                                        const int* __restrict__ skey,
                                                        const int* __restrict__ offsets,
                                                        const unsigned int* __restrict__ counts,
                                                        float* __restrict__ esum,
                                                        float* __restrict__ out) {
    __shared__ float buck[64][DIM];     // 32 KB
    __shared__ int   rid_s[64], rank_s[64], bcode_s[64];
    __shared__ int   nseg_s;
    __shared__ float lred[4];

    const int tid = threadIdx.x;
    const int w   = tid >> 6, l = tid & 63;
    const int p0  = blockIdx.x * 64;

    {
        float4* bz = (float4*)&buck[0][0];
#pragma unroll
        for (int j = 0; j < 8; ++j) bz[j * 256 + tid] = (float4){0.f, 0.f, 0.f, 0.f};
    }

    if (tid < 64) {
        int p = p0 + tid;
        int k = skey[p];
        rid_s[tid] = rowids[p];
        int f = (tid == 0) ? 1 : (k != skey[p - 1] ? 1 : 0);
        int inc = f;
#pragma unroll
        for (int off = 1; off < 64; off <<= 1) {
            int t = __shfl_up(inc, off);
            if (tid >= off) inc += t;
        }
        int rank = inc - 1;
        rank_s[tid] = rank;
        if (f) bcode_s[rank] = k;
        if (tid == 63) nseg_s = inc;
    }
    __syncthreads();

    // accumulate rows: wave w owns positions 16w..16w+15; lane l owns dims (2l, 2l+1).
    // runs are contiguous -> register-accumulate, flush to LDS bucket on segment change
    // (branch is wave-uniform: rank_s[pl] identical across lanes).
    float lsum = 0.f;
    {
        int prevb = rank_s[w * 16];
        float2 ev = *(const float2*)(embed + (size_t)bcode_s[prevb] * DIM + l * 2);
        float ra0 = 0.f, ra1 = 0.f;
#pragma unroll 4
        for (int i = 0; i < 16; ++i) {
            int pl = w * 16 + i;
            int r  = rid_s[pl];
            int b  = rank_s[pl];
            if (b != prevb) {
                atomicAdd(&buck[prevb][l * 2],     ra0);
                atomicAdd(&buck[prevb][l * 2 + 1], ra1);
                ra0 = 0.f; ra1 = 0.f;
                prevb = b;
                ev = *(const float2*)(embed + (size_t)bcode_s[b] * DIM + l * 2);
            }
            float2 xv = *(const float2*)(x + (size_t)r * DIM + l * 2);
            *(float2*)(out + (size_t)r * DIM + l * 2) = ev;     // quantize gather
            ra0 += xv.x; ra1 += xv.y;
            float d0 = ev.x - xv.x, d1 = ev.y - xv.y;
            lsum = fmaf(d0, d0, fmaf(d1, d1, lsum));
        }
        atomicAdd(&buck[prevb][l * 2],     ra0);
        atomicAdd(&buck[prevb][l * 2 + 1], ra1);
    }

#pragma unroll
    for (int s = 32; s >= 1; s >>= 1) lsum += __shfl_xor(lsum, s);
    if (l == 0) lred[w] = lsum;
    __syncthreads();

    int nseg = nseg_s;
    for (int b = w; b < nseg; b += 4) {
        int kb = bcode_s[b];
        int o  = offsets[kb];
        int c  = (int)counts[kb];
        float v0 = buck[b][l * 2], v1 = buck[b][l * 2 + 1];
        if (o >= p0 && o + c <= p0 + 64) {
            *(float2*)(esum + (size_t)kb * DIM + l * 2) = (float2){v0, v1};
        } else {
            atomicAdd(esum + (size_t)kb * DIM + l * 2,     v0);
            atomicAdd(esum + (size_t)kb * DIM + l * 2 + 1, v1);
        }
    }

    if (tid == 0) {
        float bl = (lred[0] + lred[1]) + (lred[2] + lred[3]);
        atomicAdd(out + OFF_LOSS, bl * (1.0f / ((float)NPTS * (float)DIM)));
    }
}

// ---------------- embed: new_embed = (eavg*0.99 + esum*0.01) * inv_sm ----------------
__global__ __launch_bounds__(256) void vq_embed_kernel(const float* __restrict__ eavg,
                                                       const float* __restrict__ esum,
                                                       const float* __restrict__ inv_sm,
                                                       float* __restrict__ out) {
    int i = blockIdx.x * 256 + threadIdx.x;
    int k = i >> 7;
    out[OFF_EMB + i] = fmaf(eavg[i], DECAY_F, esum[i] * ONE_MINUS_DECAY) * inv_sm[k];
}

extern "C" void kernel_launch(void* const* d_in, const int* in_sizes, int n_in,
                              void* d_out, int out_size, void* d_ws, size_t ws_size,
                              hipStream_t stream) {
    const float* x     = (const float*)d_in[0];
    const float* embed = (const float*)d_in[1];
    const float* cs    = (const float*)d_in[2];
    const float* eavg  = (const float*)d_in[3];
    float* out = (float*)d_out;

    // ws: rowpack[N] u64 | esq[K] | inv_sm[K] | counts[K] | offsets[K] | cursor[K] |
    //     rowids[N] | sidx[N] | skey[N] | esum[K*D] | Eimg 2MB   (~5.9 MB)
    unsigned long long* rowpack = (unsigned long long*)d_ws;
    float*         esq     = (float*)(rowpack + NPTS);
    float*         inv_sm  = esq + KCODES;
    unsigned int*  counts  = (unsigned int*)(inv_sm + KCODES);
    int*           offsets = (int*)(counts + KCODES);
    int*           cursor  = offsets + KCODES;
    int*           rowids  = cursor + KCODES;
    int*           sidx    = rowids + NPTS;
    int*           skey    = sidx + NPTS;
    float*         esum    = (float*)(skey + NPTS);
    unsigned char* Eimg    = (unsigned char*)(esum + KCODES * DIM);

    vq_prep_kernel<<<KCODES / 32, 256, 0, stream>>>(embed, esq, Eimg, rowpack, counts, esum, out);
    vq_main_kernel<<<NPTS / 128 * 2, 256, 0, stream>>>(x, esq, Eimg, rowpack, counts, sidx, out);
    vq_scan_kernel<<<1, 256, 0, stream>>>(counts, cs, out, offsets, cursor, inv_sm);
    vq_sort_kernel<<<NPTS / 256, 256, 0, stream>>>(sidx, cursor, rowids, skey);
    vq_segsum_kernel<<<NPTS / 64, 256, 0, stream>>>(x, embed, rowids, skey, offsets, counts, esum, out);
    vq_embed_kernel<<<(KCODES * DIM) / 256, 256, 0, stream>>>(eavg, esum, inv_sm, out);
}